// Round 4
// baseline (153.908 us; speedup 1.0000x reference)
//
#include <hip/hip_runtime.h>
#include <hip/hip_bf16.h>

#define NB 8192        // batch rows
#define M1T 139264     // NB * 17 rows in layer-1

typedef __attribute__((ext_vector_type(8))) short bf16x8;
typedef __attribute__((ext_vector_type(16))) float f32x16;

__device__ __forceinline__ unsigned short f2b(float f) {
  union { float f; unsigned u; } v; v.f = f;
  unsigned r = v.u + 0x7fffu + ((v.u >> 16) & 1u);   // RNE
  return (unsigned short)(r >> 16);
}
__device__ __forceinline__ float b2f(unsigned u16) {
  union { unsigned u; float f; } v; v.u = u16 << 16;
  return v.f;
}
__device__ __forceinline__ uint4 pack8u(float a0, float a1, float a2, float a3,
                                        float a4, float a5, float a6, float a7) {
  uint4 v;
  v.x = (unsigned)f2b(a0) | ((unsigned)f2b(a1) << 16);
  v.y = (unsigned)f2b(a2) | ((unsigned)f2b(a3) << 16);
  v.z = (unsigned)f2b(a4) | ((unsigned)f2b(a5) << 16);
  v.w = (unsigned)f2b(a6) | ((unsigned)f2b(a7) << 16);
  return v;
}

#define GLDS16(g, l)                                                          \
  __builtin_amdgcn_global_load_lds(                                           \
      (const __attribute__((address_space(1))) unsigned int*)(const void*)(g),\
      (__attribute__((address_space(3))) unsigned int*)(void*)(l), 16, 0, 0)

// ---- kernel 0: W1/W2 fp32 -> bf16, PRE-SWIZZLED per-kt tile layout ----
__global__ void convert_w(const float* __restrict__ W1, const float* __restrict__ W2,
                          unsigned short* __restrict__ W1s, unsigned short* __restrict__ W2s) {
  int i = blockIdx.x * 256 + threadIdx.x;  // 0..65535, one float4 each
  const float* W; unsigned short* out; int f4;
  if (i < 32768) { W = W1; out = W1s; f4 = i; }
  else           { W = W2; out = W2s; f4 = i - 32768; }
  int n  = (f4 * 4) >> 9;
  int c0 = (f4 * 4) & 511;
  int kt = c0 >> 6;
  int slot = (c0 & 63) >> 3;
  int e  = c0 & 7;               // 0 or 4
  int sw = slot ^ (n & 7);
  float4 v = *((const float4*)W + f4);
  ushort4 o;
  o.x = f2b(v.x); o.y = f2b(v.y); o.z = f2b(v.z); o.w = f2b(v.w);
  *(ushort4*)(out + kt * 16384 + n * 64 + sw * 8 + e) = o;
}

// ---- layer 1: h1 = relu([self || mean4(neigh2)] @ W1^T), bf16 out ----
// BM=64, BN=256, 512 threads = 8 waves. 2-deep gather prefetch, counted vmcnt,
// ONE barrier per K-step, dbuf A+B.
__global__ __launch_bounds__(512, 4)
void sage_l1(const float* __restrict__ feats,
             const unsigned short* __restrict__ Wbs,
             const int* __restrict__ batch_nodes,
             const int* __restrict__ neigh1,
             const int* __restrict__ neigh2,
             unsigned short* __restrict__ h1b)
{
  __shared__ __align__(16) unsigned short As[2][64 * 64];    // 2 x 8 KB
  __shared__ __align__(16) unsigned short Bs[2][256 * 64];   // 2 x 32 KB
  const int tid = threadIdx.x;
  const int m0 = blockIdx.x * 64;
  const int w = tid >> 6, lane = tid & 63, l31 = lane & 31, lh = lane >> 5;
  const int mh = w & 1, nq = w >> 1;
  const int m = tid >> 3, slot = tid & 7;
  const int r = m0 + m;

  const int self = (r < NB) ? batch_nodes[r] : neigh1[r - NB];
  const int4 nb = *(const int4*)(neigh2 + (size_t)r * 4);
  const char* fb = (const char*)feats;
  const unsigned so  = (unsigned)self * 1024u + (unsigned)slot * 32u;
  const unsigned no0 = (unsigned)nb.x * 1024u + (unsigned)slot * 32u;
  const unsigned no1 = (unsigned)nb.y * 1024u + (unsigned)slot * 32u;
  const unsigned no2 = (unsigned)nb.z * 1024u + (unsigned)slot * 32u;
  const unsigned no3 = (unsigned)nb.w * 1024u + (unsigned)slot * 32u;
  const int arowC = mh * 32 + l31;
  const int n0C = nq * 64 + l31, n1C = n0C + 32;

  f32x16 acc0 = {}, acc1 = {};
  float4 a0[8], a1[8];

  #define L1_LOADS(KT, AR)                                                    \
    do { if ((KT) < 4) {                                                      \
           AR[0] = *(const float4*)(fb + so + (KT) * 256);                    \
           AR[1] = *(const float4*)(fb + so + (KT) * 256 + 16);               \
         } else {                                                             \
           const int _kb = ((KT) - 4) * 256;                                  \
           AR[0] = *(const float4*)(fb + no0 + _kb);                          \
           AR[1] = *(const float4*)(fb + no0 + _kb + 16);                     \
           AR[2] = *(const float4*)(fb + no1 + _kb);                          \
           AR[3] = *(const float4*)(fb + no1 + _kb + 16);                     \
           AR[4] = *(const float4*)(fb + no2 + _kb);                          \
           AR[5] = *(const float4*)(fb + no2 + _kb + 16);                     \
           AR[6] = *(const float4*)(fb + no3 + _kb);                          \
           AR[7] = *(const float4*)(fb + no3 + _kb + 16);                     \
         } } while (0)

  #define L1_BISSUE(KT)                                                       \
    do { const unsigned short* _s = Wbs + (size_t)(KT) * 16384;               \
         unsigned short* _d = &Bs[(KT) & 1][0];                               \
         _Pragma("unroll")                                                    \
         for (int _q = 0; _q < 4; ++_q) {                                     \
           int _i = _q * 512 + tid;                                           \
           GLDS16(_s + (size_t)_i * 8, _d + _i * 8);                          \
         } } while (0)

  #define L1_CONV(KT, AR, AV)                                                 \
    do { if ((KT) < 4) {                                                      \
           AV = pack8u(AR[0].x, AR[0].y, AR[0].z, AR[0].w,                    \
                       AR[1].x, AR[1].y, AR[1].z, AR[1].w);                   \
         } else {                                                             \
           float s0 = AR[0].x + AR[2].x + AR[4].x + AR[6].x;                  \
           float s1 = AR[0].y + AR[2].y + AR[4].y + AR[6].y;                  \
           float s2 = AR[0].z + AR[2].z + AR[4].z + AR[6].z;                  \
           float s3 = AR[0].w + AR[2].w + AR[4].w + AR[6].w;                  \
           float s4 = AR[1].x + AR[3].x + AR[5].x + AR[7].x;                  \
           float s5 = AR[1].y + AR[3].y + AR[5].y + AR[7].y;                  \
           float s6 = AR[1].z + AR[3].z + AR[5].z + AR[7].z;                  \
           float s7 = AR[1].w + AR[3].w + AR[5].w + AR[7].w;                  \
           AV = pack8u(s0 * 0.25f, s1 * 0.25f, s2 * 0.25f, s3 * 0.25f,       \
                       s4 * 0.25f, s5 * 0.25f, s6 * 0.25f, s7 * 0.25f);      \
         } } while (0)

  // One K-step. Queue entering: [A(KT), B(KT), A(KT+1)].
  #define L1_STEP(KT, AR, NCNT)                                               \
    do { uint4 _av;                                                           \
         L1_CONV(KT, AR, _av);   /* auto-wait drains A(KT), leaves B,A+1 */   \
         *(uint4*)(&As[(KT) & 1][m * 64 + ((slot ^ (m & 7)) << 3)]) = _av;    \
         asm volatile("s_waitcnt vmcnt(" #NCNT ") lgkmcnt(0)" ::: "memory");  \
         __builtin_amdgcn_s_barrier();                                        \
         if ((KT) < 7) L1_BISSUE((KT) + 1);                                   \
         if ((KT) < 6) L1_LOADS((KT) + 2, AR);                                \
         __builtin_amdgcn_sched_barrier(0);                                   \
         __builtin_amdgcn_s_setprio(1);                                       \
         _Pragma("unroll")                                                    \
         for (int _kk = 0; _kk < 4; ++_kk) {                                  \
           int _sl = _kk * 2 + lh;                                            \
           bf16x8 _a  = *(const bf16x8*)(&As[(KT) & 1][arowC * 64 + ((_sl ^ (arowC & 7)) << 3)]); \
           bf16x8 _b0 = *(const bf16x8*)(&Bs[(KT) & 1][n0C * 64 + ((_sl ^ (n0C & 7)) << 3)]);     \
           bf16x8 _b1 = *(const bf16x8*)(&Bs[(KT) & 1][n1C * 64 + ((_sl ^ (n1C & 7)) << 3)]);     \
           acc0 = __builtin_amdgcn_mfma_f32_32x32x16_bf16(_a, _b0, acc0, 0, 0, 0);                \
           acc1 = __builtin_amdgcn_mfma_f32_32x32x16_bf16(_a, _b1, acc1, 0, 0, 0);                \
         }                                                                    \
         __builtin_amdgcn_s_setprio(0);                                       \
    } while (0)

  // prologue: queue = [A(0), B(0), A(1)]
  L1_LOADS(0, a0);
  L1_BISSUE(0);
  L1_LOADS(1, a1);
  __builtin_amdgcn_sched_barrier(0);

  L1_STEP(0, a0, 2);
  L1_STEP(1, a1, 2);
  L1_STEP(2, a0, 2);
  L1_STEP(3, a1, 8);
  L1_STEP(4, a0, 8);
  L1_STEP(5, a1, 8);
  L1_STEP(6, a0, 8);
  L1_STEP(7, a1, 0);

  #undef L1_LOADS
  #undef L1_BISSUE
  #undef L1_CONV
  #undef L1_STEP

  // epilogue: relu -> bf16 h1
  #pragma unroll
  for (int q = 0; q < 16; ++q) {
    int row = m0 + mh * 32 + (q & 3) + 8 * (q >> 2) + 4 * lh;
    int col0 = nq * 64 + l31;
    float v0 = acc0[q], v1 = acc1[q];
    v0 = v0 > 0.f ? v0 : 0.f;
    v1 = v1 > 0.f ? v1 : 0.f;
    h1b[(size_t)row * 256 + col0] = f2b(v0);
    h1b[(size_t)row * 256 + col0 + 32] = f2b(v1);
  }
}

// ---- layer 2: out = relu([h1_self || mean16(h1_neigh)] @ W2^T), fp32 out ----
// BM=32 -> 256 blocks, 512 threads = 8 waves; wave w owns cols w*32.
__global__ __launch_bounds__(512, 4)
void sage_l2(const unsigned short* __restrict__ h1b,
             const unsigned short* __restrict__ Wbs,
             float* __restrict__ out)
{
  __shared__ __align__(16) unsigned short As[2][32 * 64];    // 2 x 4 KB
  __shared__ __align__(16) unsigned short Bs[2][256 * 64];   // 2 x 32 KB
  const int tid = threadIdx.x;
  const int m0 = blockIdx.x * 32;
  const int w = tid >> 6, lane = tid & 63, l31 = lane & 31, lh = lane >> 5;
  const int m = tid >> 4, slot = tid & 15;        // 32 rows x 16 slots of 4 elems
  const int r = m0 + m;
  const char* hb = (const char*)h1b;
  const unsigned so = (unsigned)r * 512u + (unsigned)slot * 8u;
  const unsigned ao = (unsigned)(NB + r * 16) * 512u + (unsigned)slot * 8u;
  const int arowC = l31;
  const int n0C = w * 32 + l31;

  f32x16 acc = {};
  uint2 b0r[16], b1r[16];

  #define L2_LOADS(KT, BR)                                                    \
    do { if ((KT) < 4) {                                                      \
           BR[0] = *(const uint2*)(hb + so + (KT) * 128);                     \
         } else {                                                             \
           _Pragma("unroll")                                                  \
           for (int _j = 0; _j < 16; ++_j)                                    \
             BR[_j] = *(const uint2*)(hb + ao + _j * 512 + ((KT) - 4) * 128); \
         } } while (0)

  #define L2_BISSUE(KT)                                                       \
    do { const unsigned short* _s = Wbs + (size_t)(KT) * 16384;               \
         unsigned short* _d = &Bs[(KT) & 1][0];                               \
         _Pragma("unroll")                                                    \
         for (int _q = 0; _q < 4; ++_q) {                                     \
           int _i = _q * 512 + tid;                                           \
           GLDS16(_s + (size_t)_i * 8, _d + _i * 8);                          \
         } } while (0)

  #define L2_CONV(KT, BR, AV)                                                 \
    do { if ((KT) < 4) { AV = BR[0]; }                                        \
         else {                                                               \
           float s0 = 0, s1 = 0, s2 = 0, s3 = 0;                              \
           _Pragma("unroll")                                                  \
           for (int _j = 0; _j < 16; ++_j) {                                  \
             s0 += b2f(BR[_j].x & 0xffffu); s1 += b2f(BR[_j].x >> 16);        \
             s2 += b2f(BR[_j].y & 0xffffu); s3 += b2f(BR[_j].y >> 16);        \
           }                                                                  \
           const float _q16 = 1.0f / 16.0f;                                   \
           AV.x = (unsigned)f2b(s0 * _q16) | ((unsigned)f2b(s1 * _q16) << 16);\
           AV.y = (unsigned)f2b(s2 * _q16) | ((unsigned)f2b(s3 * _q16) << 16);\
         } } while (0)

  #define L2_STEP(KT, BR, NCNT)                                               \
    do { uint2 _av;                                                           \
         L2_CONV(KT, BR, _av);                                                \
         *(uint2*)(&As[(KT) & 1][m * 64 + (((slot >> 1) ^ (m & 7)) << 3) + (slot & 1) * 4]) = _av; \
         asm volatile("s_waitcnt vmcnt(" #NCNT ") lgkmcnt(0)" ::: "memory");  \
         __builtin_amdgcn_s_barrier();                                        \
         if ((KT) < 7) L2_BISSUE((KT) + 1);                                   \
         if ((KT) < 6) L2_LOADS((KT) + 2, BR);                                \
         __builtin_amdgcn_sched_barrier(0);                                   \
         __builtin_amdgcn_s_setprio(1);                                       \
         _Pragma("unroll")                                                    \
         for (int _kk = 0; _kk < 4; ++_kk) {                                  \
           int _sl = _kk * 2 + lh;                                            \
           bf16x8 _a = *(const bf16x8*)(&As[(KT) & 1][arowC * 64 + ((_sl ^ (arowC & 7)) << 3)]); \
           bf16x8 _b = *(const bf16x8*)(&Bs[(KT) & 1][n0C * 64 + ((_sl ^ (n0C & 7)) << 3)]);     \
           acc = __builtin_amdgcn_mfma_f32_32x32x16_bf16(_a, _b, acc, 0, 0, 0);                  \
         }                                                                    \
         __builtin_amdgcn_s_setprio(0);                                       \
    } while (0)

  L2_LOADS(0, b0r);
  L2_BISSUE(0);
  L2_LOADS(1, b1r);
  __builtin_amdgcn_sched_barrier(0);

  L2_STEP(0, b0r, 1);
  L2_STEP(1, b1r, 1);
  L2_STEP(2, b0r, 1);
  L2_STEP(3, b1r, 16);
  L2_STEP(4, b0r, 16);
  L2_STEP(5, b1r, 16);
  L2_STEP(6, b0r, 16);
  L2_STEP(7, b1r, 0);

  #undef L2_LOADS
  #undef L2_BISSUE
  #undef L2_CONV
  #undef L2_STEP

  #pragma unroll
  for (int q = 0; q < 16; ++q) {
    int row = m0 + (q & 3) + 8 * (q >> 2) + 4 * lh;
    int col = n0C;
    float v = acc[q];
    out[(size_t)row * 256 + col] = v > 0.f ? v : 0.f;
  }
}

extern "C" void kernel_launch(void* const* d_in, const int* in_sizes, int n_in,
                              void* d_out, int out_size, void* d_ws, size_t ws_size,
                              hipStream_t stream) {
  const float* feats       = (const float*)d_in[0];
  const float* W1          = (const float*)d_in[1];
  const float* W2          = (const float*)d_in[2];
  const int*   batch_nodes = (const int*)d_in[3];
  const int*   neigh1      = (const int*)d_in[4];
  const int*   neigh2      = (const int*)d_in[5];
  float* out = (float*)d_out;

  unsigned short* W1s = (unsigned short*)d_ws;            // 131072 elems (swizzled)
  unsigned short* W2s = W1s + 131072;                     // 131072 elems (swizzled)
  unsigned short* h1b = W2s + 131072;                     // 139264*256 elems (~71 MB)

  hipLaunchKernelGGL(convert_w, dim3(256), dim3(256), 0, stream, W1, W2, W1s, W2s);
  hipLaunchKernelGGL(sage_l1, dim3(M1T / 64), dim3(512), 0, stream,
                     feats, W1s, batch_nodes, neigh1, neigh2, h1b);
  hipLaunchKernelGGL(sage_l2, dim3(NB / 32), dim3(512), 0, stream, h1b, W2s, out);
}

// Round 5
// 126.910 us; speedup vs baseline: 1.2127x; 1.2127x over previous
//
#include <hip/hip_runtime.h>
#include <hip/hip_bf16.h>

#define NB 8192        // batch rows
#define M1T 139264     // NB + NB*16 rows in layer-1
#define SELFB 128      // NB/64 self blocks in l1

typedef __attribute__((ext_vector_type(8))) short bf16x8;
typedef __attribute__((ext_vector_type(16))) float f32x16;

__device__ __forceinline__ unsigned short f2b(float f) {
  union { float f; unsigned u; } v; v.f = f;
  unsigned r = v.u + 0x7fffu + ((v.u >> 16) & 1u);   // RNE
  return (unsigned short)(r >> 16);
}
__device__ __forceinline__ uint4 pack8u(float a0, float a1, float a2, float a3,
                                        float a4, float a5, float a6, float a7) {
  uint4 v;
  v.x = (unsigned)f2b(a0) | ((unsigned)f2b(a1) << 16);
  v.y = (unsigned)f2b(a2) | ((unsigned)f2b(a3) << 16);
  v.z = (unsigned)f2b(a4) | ((unsigned)f2b(a5) << 16);
  v.w = (unsigned)f2b(a6) | ((unsigned)f2b(a7) << 16);
  return v;
}

#define GLDS16(g, l)                                                          \
  __builtin_amdgcn_global_load_lds(                                           \
      (const __attribute__((address_space(1))) unsigned int*)(const void*)(g),\
      (__attribute__((address_space(3))) unsigned int*)(void*)(l), 16, 0, 0)

// ---- kernel 0: W1/W2 fp32 -> bf16, PRE-SWIZZLED per-kt tile layout ----
__global__ void convert_w(const float* __restrict__ W1, const float* __restrict__ W2,
                          unsigned short* __restrict__ W1s, unsigned short* __restrict__ W2s) {
  int i = blockIdx.x * 256 + threadIdx.x;  // 0..65535, one float4 each
  const float* W; unsigned short* out; int f4;
  if (i < 32768) { W = W1; out = W1s; f4 = i; }
  else           { W = W2; out = W2s; f4 = i - 32768; }
  int n  = (f4 * 4) >> 9;
  int c0 = (f4 * 4) & 511;
  int kt = c0 >> 6;
  int slot = (c0 & 63) >> 3;
  int e  = c0 & 7;               // 0 or 4
  int sw = slot ^ (n & 7);
  float4 v = *((const float4*)W + f4);
  ushort4 o;
  o.x = f2b(v.x); o.y = f2b(v.y); o.z = f2b(v.z); o.w = f2b(v.w);
  *(ushort4*)(out + kt * 16384 + n * 64 + sw * 8 + e) = o;
}

// ---- layer 1: relu([self || mean4(neigh2)] @ W1^T) ----
// Self blocks (bi < 128) write rows into A2 cols 0..255.
// Neighbor blocks reduce 16-row groups in-register -> A2 cols 256..511.
__global__ __launch_bounds__(512, 4)
void sage_l1(const float* __restrict__ feats,
             const unsigned short* __restrict__ Wbs,
             const int* __restrict__ batch_nodes,
             const int* __restrict__ neigh1,
             const int* __restrict__ neigh2,
             unsigned short* __restrict__ A2)
{
  __shared__ __align__(16) unsigned short As[2][64 * 64];    // 2 x 8 KB
  __shared__ __align__(16) unsigned short Bs[2][256 * 64];   // 2 x 32 KB
  const int tid = threadIdx.x;
  const int m0 = blockIdx.x * 64;
  const int w = tid >> 6, lane = tid & 63, l31 = lane & 31, lh = lane >> 5;
  const int mh = w & 1, nq = w >> 1;
  const int m = tid >> 3, slot = tid & 7;
  const int r = m0 + m;

  const int self = (r < NB) ? batch_nodes[r] : neigh1[r - NB];
  const int4 nb = *(const int4*)(neigh2 + (size_t)r * 4);
  const char* fb = (const char*)feats;
  const unsigned so  = (unsigned)self * 1024u + (unsigned)slot * 32u;
  const unsigned no0 = (unsigned)nb.x * 1024u + (unsigned)slot * 32u;
  const unsigned no1 = (unsigned)nb.y * 1024u + (unsigned)slot * 32u;
  const unsigned no2 = (unsigned)nb.z * 1024u + (unsigned)slot * 32u;
  const unsigned no3 = (unsigned)nb.w * 1024u + (unsigned)slot * 32u;
  const int arowC = mh * 32 + l31;
  const int n0C = nq * 64 + l31, n1C = n0C + 32;

  f32x16 acc0 = {}, acc1 = {};
  float4 a0[8], a1[8];

  #define L1_LOADS(KT, AR)                                                    \
    do { if ((KT) < 4) {                                                      \
           AR[0] = *(const float4*)(fb + so + (KT) * 256);                    \
           AR[1] = *(const float4*)(fb + so + (KT) * 256 + 16);               \
         } else {                                                             \
           const int _kb = ((KT) - 4) * 256;                                  \
           AR[0] = *(const float4*)(fb + no0 + _kb);                          \
           AR[1] = *(const float4*)(fb + no0 + _kb + 16);                     \
           AR[2] = *(const float4*)(fb + no1 + _kb);                          \
           AR[3] = *(const float4*)(fb + no1 + _kb + 16);                     \
           AR[4] = *(const float4*)(fb + no2 + _kb);                          \
           AR[5] = *(const float4*)(fb + no2 + _kb + 16);                     \
           AR[6] = *(const float4*)(fb + no3 + _kb);                          \
           AR[7] = *(const float4*)(fb + no3 + _kb + 16);                     \
         } } while (0)

  #define L1_BISSUE(KT)                                                       \
    do { const unsigned short* _s = Wbs + (size_t)(KT) * 16384;               \
         unsigned short* _d = &Bs[(KT) & 1][0];                               \
         _Pragma("unroll")                                                    \
         for (int _q = 0; _q < 4; ++_q) {                                     \
           int _i = _q * 512 + tid;                                           \
           GLDS16(_s + (size_t)_i * 8, _d + _i * 8);                          \
         } } while (0)

  #define L1_CONV(KT, AR, AV)                                                 \
    do { if ((KT) < 4) {                                                      \
           AV = pack8u(AR[0].x, AR[0].y, AR[0].z, AR[0].w,                    \
                       AR[1].x, AR[1].y, AR[1].z, AR[1].w);                   \
         } else {                                                             \
           float s0 = AR[0].x + AR[2].x + AR[4].x + AR[6].x;                  \
           float s1 = AR[0].y + AR[2].y + AR[4].y + AR[6].y;                  \
           float s2 = AR[0].z + AR[2].z + AR[4].z + AR[6].z;                  \
           float s3 = AR[0].w + AR[2].w + AR[4].w + AR[6].w;                  \
           float s4 = AR[1].x + AR[3].x + AR[5].x + AR[7].x;                  \
           float s5 = AR[1].y + AR[3].y + AR[5].y + AR[7].y;                  \
           float s6 = AR[1].z + AR[3].z + AR[5].z + AR[7].z;                  \
           float s7 = AR[1].w + AR[3].w + AR[5].w + AR[7].w;                  \
           AV = pack8u(s0 * 0.25f, s1 * 0.25f, s2 * 0.25f, s3 * 0.25f,       \
                       s4 * 0.25f, s5 * 0.25f, s6 * 0.25f, s7 * 0.25f);      \
         } } while (0)

  // One K-step. Queue entering: [A(KT), B(KT), A(KT+1)].
  #define L1_STEP(KT, AR, NCNT)                                               \
    do { uint4 _av;                                                           \
         L1_CONV(KT, AR, _av);   /* auto-wait drains A(KT), leaves B,A+1 */   \
         *(uint4*)(&As[(KT) & 1][m * 64 + ((slot ^ (m & 7)) << 3)]) = _av;    \
         asm volatile("s_waitcnt vmcnt(" #NCNT ") lgkmcnt(0)" ::: "memory");  \
         __builtin_amdgcn_s_barrier();                                        \
         if ((KT) < 7) L1_BISSUE((KT) + 1);                                   \
         if ((KT) < 6) L1_LOADS((KT) + 2, AR);                                \
         __builtin_amdgcn_sched_barrier(0);                                   \
         __builtin_amdgcn_s_setprio(1);                                       \
         _Pragma("unroll")                                                    \
         for (int _kk = 0; _kk < 4; ++_kk) {                                  \
           int _sl = _kk * 2 + lh;                                            \
           bf16x8 _a  = *(const bf16x8*)(&As[(KT) & 1][arowC * 64 + ((_sl ^ (arowC & 7)) << 3)]); \
           bf16x8 _b0 = *(const bf16x8*)(&Bs[(KT) & 1][n0C * 64 + ((_sl ^ (n0C & 7)) << 3)]);     \
           bf16x8 _b1 = *(const bf16x8*)(&Bs[(KT) & 1][n1C * 64 + ((_sl ^ (n1C & 7)) << 3)]);     \
           acc0 = __builtin_amdgcn_mfma_f32_32x32x16_bf16(_a, _b0, acc0, 0, 0, 0);                \
           acc1 = __builtin_amdgcn_mfma_f32_32x32x16_bf16(_a, _b1, acc1, 0, 0, 0);                \
         }                                                                    \
         __builtin_amdgcn_s_setprio(0);                                       \
    } while (0)

  // prologue: queue = [A(0), B(0), A(1)]
  L1_LOADS(0, a0);
  L1_BISSUE(0);
  L1_LOADS(1, a1);
  __builtin_amdgcn_sched_barrier(0);

  L1_STEP(0, a0, 2);
  L1_STEP(1, a1, 2);
  L1_STEP(2, a0, 2);
  L1_STEP(3, a1, 8);
  L1_STEP(4, a0, 8);
  L1_STEP(5, a1, 8);
  L1_STEP(6, a0, 8);
  L1_STEP(7, a1, 0);

  #undef L1_LOADS
  #undef L1_BISSUE
  #undef L1_CONV
  #undef L1_STEP

  if (blockIdx.x < SELFB) {
    // self rows -> A2 cols [0,256), row-major stride 512
    #pragma unroll
    for (int q = 0; q < 16; ++q) {
      int row = m0 + mh * 32 + (q & 3) + 8 * (q >> 2) + 4 * lh;
      int col0 = nq * 64 + l31;
      float v0 = acc0[q], v1 = acc1[q];
      v0 = v0 > 0.f ? v0 : 0.f;
      v1 = v1 > 0.f ? v1 : 0.f;
      A2[(size_t)row * 512 + col0] = f2b(v0);
      A2[(size_t)row * 512 + col0 + 32] = f2b(v1);
    }
  } else {
    // neighbor rows: relu then mean over 16-row groups -> A2 cols [256,512)
    // q 0..7 covers local rows mh*32+{0..15} (group 2mh); q 8..15 -> group 2mh+1
    const int bi = blockIdx.x - SELFB;
    #pragma unroll
    for (int gi = 0; gi < 2; ++gi) {
      float sA = 0.f, sB = 0.f;
      #pragma unroll
      for (int q = gi * 8; q < gi * 8 + 8; ++q) {
        float v0 = acc0[q], v1 = acc1[q];
        sA += (v0 > 0.f ? v0 : 0.f);
        sB += (v1 > 0.f ? v1 : 0.f);
      }
      sA += __shfl_xor(sA, 32, 64);   // combine lh halves -> full 16-row sum
      sB += __shfl_xor(sB, 32, 64);
      if (lh == 0) {
        int gr = bi * 4 + mh * 2 + gi;
        int col = 256 + nq * 64 + l31;
        A2[(size_t)gr * 512 + col] = f2b(sA * 0.0625f);
        A2[(size_t)gr * 512 + col + 32] = f2b(sB * 0.0625f);
      }
    }
  }
}

// ---- layer 2: dense [8192 x 512](bf16) @ W2^T, relu, fp32 out ----
// BM=32 -> 256 blocks, 256 threads = 4 waves; wave w owns cols w*64.
// Both A and B staged via global_load_lds (A source pre-swizzled per-lane).
__global__ __launch_bounds__(256, 2)
void sage_l2(const unsigned short* __restrict__ A2,
             const unsigned short* __restrict__ Wbs,
             float* __restrict__ out)
{
  __shared__ __align__(16) unsigned short As[2][32 * 64];    // 2 x 4 KB
  __shared__ __align__(16) unsigned short Bs[2][256 * 64];   // 2 x 32 KB
  const int tid = threadIdx.x;
  const int m0 = blockIdx.x * 32;
  const int w = tid >> 6, lane = tid & 63, l31 = lane & 31, lh = lane >> 5;
  const int mA = tid >> 3, swA = tid & 7;
  const int arowC = l31;
  const int n0C = w * 64 + l31, n1C = n0C + 32;
  // pre-swizzled A source: LDS slot (mA, swA) holds data for slot swA^(mA&7)
  const unsigned short* aSrc = A2 + (size_t)(m0 + mA) * 512 + (swA ^ (mA & 7)) * 8;

  f32x16 acc0 = {}, acc1 = {};

  #define L2_STAGE(KT)                                                        \
    do { const unsigned short* _s = Wbs + (size_t)(KT) * 16384;               \
         unsigned short* _d = &Bs[(KT) & 1][0];                               \
         _Pragma("unroll")                                                    \
         for (int _q = 0; _q < 8; ++_q) {                                     \
           int _i = _q * 256 + tid;                                           \
           GLDS16(_s + (size_t)_i * 8, _d + _i * 8);                          \
         }                                                                    \
         GLDS16(aSrc + (KT) * 64, &As[(KT) & 1][mA * 64 + swA * 8]);          \
    } while (0)

  L2_STAGE(0);
  asm volatile("s_waitcnt vmcnt(0)" ::: "memory");
  __builtin_amdgcn_s_barrier();

  #pragma unroll
  for (int kt = 0; kt < 8; ++kt) {
    if (kt < 7) L2_STAGE(kt + 1);                // into buf^1, safe vs reads of buf
    __builtin_amdgcn_s_setprio(1);
    #pragma unroll
    for (int kk = 0; kk < 4; ++kk) {
      int sl = kk * 2 + lh;
      bf16x8 a  = *(const bf16x8*)(&As[kt & 1][arowC * 64 + ((sl ^ (arowC & 7)) << 3)]);
      bf16x8 b0 = *(const bf16x8*)(&Bs[kt & 1][n0C * 64 + ((sl ^ (n0C & 7)) << 3)]);
      bf16x8 b1 = *(const bf16x8*)(&Bs[kt & 1][n1C * 64 + ((sl ^ (n1C & 7)) << 3)]);
      acc0 = __builtin_amdgcn_mfma_f32_32x32x16_bf16(a, b0, acc0, 0, 0, 0);
      acc1 = __builtin_amdgcn_mfma_f32_32x32x16_bf16(a, b1, acc1, 0, 0, 0);
    }
    __builtin_amdgcn_s_setprio(0);
    asm volatile("s_waitcnt vmcnt(0)" ::: "memory");
    __builtin_amdgcn_s_barrier();
  }
  #undef L2_STAGE

  #pragma unroll
  for (int q = 0; q < 16; ++q) {
    int row = m0 + (q & 3) + 8 * (q >> 2) + 4 * lh;
    float v0 = acc0[q], v1 = acc1[q];
    out[(size_t)row * 256 + n0C] = v0 > 0.f ? v0 : 0.f;
    out[(size_t)row * 256 + n1C] = v1 > 0.f ? v1 : 0.f;
  }
}

extern "C" void kernel_launch(void* const* d_in, const int* in_sizes, int n_in,
                              void* d_out, int out_size, void* d_ws, size_t ws_size,
                              hipStream_t stream) {
  const float* feats       = (const float*)d_in[0];
  const float* W1          = (const float*)d_in[1];
  const float* W2          = (const float*)d_in[2];
  const int*   batch_nodes = (const int*)d_in[3];
  const int*   neigh1      = (const int*)d_in[4];
  const int*   neigh2      = (const int*)d_in[5];
  float* out = (float*)d_out;

  unsigned short* W1s = (unsigned short*)d_ws;            // 131072 elems (swizzled)
  unsigned short* W2s = W1s + 131072;                     // 131072 elems (swizzled)
  unsigned short* A2  = W2s + 131072;                     // 8192*512 bf16 (8 MB)

  hipLaunchKernelGGL(convert_w, dim3(256), dim3(256), 0, stream, W1, W2, W1s, W2s);
  hipLaunchKernelGGL(sage_l1, dim3(M1T / 64), dim3(512), 0, stream,
                     feats, W1s, batch_nodes, neigh1, neigh2, A2);
  hipLaunchKernelGGL(sage_l2, dim3(NB / 32), dim3(256), 0, stream, A2, W2s, out);
}